// Round 1
// baseline (360.731 us; speedup 1.0000x reference)
//
#include <hip/hip_runtime.h>
#include <math.h>

// LIF-R neuron step, N=8192.
// Dominant cost: w @ g matvec (256 MiB fp32, read once -> HBM-bound).
// Outputs: d_out = [v_new (N), spiked_soft (N)] as float32.
// Hidden state (g_new, theta_new) is never returned -> not computed.

#define BLOCK 256

__global__ __launch_bounds__(BLOCK) void lif_r_fused(
    const float* __restrict__ x_in,
    const float* __restrict__ v,
    const float* __restrict__ g,
    const float* __restrict__ theta_s,
    const float* __restrict__ w,
    const float* __restrict__ v_rest,
    float* __restrict__ out,
    int n)
{
    const int row = blockIdx.x;
    const int tid = threadIdx.x;

    // --- dot(w[row, :], g) with float4 coalesced loads -------------------
    const float4* __restrict__ wrow =
        reinterpret_cast<const float4*>(w + (size_t)row * (size_t)n);
    const float4* __restrict__ g4 = reinterpret_cast<const float4*>(g);

    const int nvec = n >> 2;          // float4 elements per row (2048 @ n=8192)
    float acc = 0.0f;
    #pragma unroll 4
    for (int idx = tid; idx < nvec; idx += BLOCK) {
        float4 wv = wrow[idx];
        float4 gv = g4[idx];
        acc = fmaf(wv.x, gv.x, acc);
        acc = fmaf(wv.y, gv.y, acc);
        acc = fmaf(wv.z, gv.z, acc);
        acc = fmaf(wv.w, gv.w, acc);
    }

    // --- wave (64-lane) reduce, then cross-wave via LDS ------------------
    #pragma unroll
    for (int off = 32; off > 0; off >>= 1)
        acc += __shfl_down(acc, off, 64);

    __shared__ float partial[BLOCK / 64];
    const int wave = tid >> 6;
    const int lane = tid & 63;
    if (lane == 0) partial[wave] = acc;
    __syncthreads();

    // --- LIF elementwise update (lane 0 of block) ------------------------
    if (tid == 0) {
        float dot = 0.0f;
        #pragma unroll
        for (int i = 0; i < BLOCK / 64; ++i) dot += partial[i];

        const float I  = dot + x_in[row];
        const float vv = v[row];
        const float vr = v_rest[row];
        const float th = theta_s[row];

        // dv = v_rest - v + I/C_M ; v_next = v + dv
        const float v_next = vv + (vr - vv + I / 0.05f);

        // soft spike: sigmoid(v_next - theta_s)
        const float z = v_next - th;
        const float s_soft = 1.0f / (1.0f + expf(-z));

        // hard spike gating + reset
        const bool  spiked  = (v_next >= th);
        const float v_reset = vr + 0.15f * (vv - vr) - 12.0f;
        const float v_new   = spiked ? v_reset : v_next;

        out[row]     = v_new;
        out[n + row] = s_soft;
    }
}

extern "C" void kernel_launch(void* const* d_in, const int* in_sizes, int n_in,
                              void* d_out, int out_size, void* d_ws, size_t ws_size,
                              hipStream_t stream) {
    // setup_inputs order: x_in, v, g, theta_s, w, v_rest, tau_g
    const float* x_in    = (const float*)d_in[0];
    const float* v       = (const float*)d_in[1];
    const float* g       = (const float*)d_in[2];
    const float* theta_s = (const float*)d_in[3];
    const float* w       = (const float*)d_in[4];
    const float* v_rest  = (const float*)d_in[5];
    // d_in[6] (tau_g) only affects hidden state g_new -> unused.

    const int n = in_sizes[0];            // 8192
    float* out = (float*)d_out;           // [v_new | spiked_soft]

    lif_r_fused<<<n, BLOCK, 0, stream>>>(x_in, v, g, theta_s, w, v_rest, out, n);
}

// Round 3
// 360.203 us; speedup vs baseline: 1.0015x; 1.0015x over previous
//
#include <hip/hip_runtime.h>
#include <math.h>

// LIF-R neuron step, N=8192.
// Dominant cost: w @ g matvec (256 MiB fp32, read once -> HBM-bound, ~43 us roofline).
// Outputs: d_out = [v_new (N), spiked_soft (N)] as float32.
// Hidden state (g_new, theta_new, tau_g) never observable -> not computed.
//
// R3 = R2 resubmit (infra timeout, never ran) + dual accumulators:
//  - compile-time trip count (N=8192) -> all 8 w-row dwordx4 loads issued
//    before any waitcnt (deep memory-level parallelism);
//  - acc0/acc1 split halves the dependent-FMA chain.

#define BLOCK 256

template <int NV>  // float4 elements of the row handled per thread
__global__ __launch_bounds__(BLOCK) void lif_r_fused(
    const float* __restrict__ x_in,
    const float* __restrict__ v,
    const float* __restrict__ g,
    const float* __restrict__ theta_s,
    const float* __restrict__ w,
    const float* __restrict__ v_rest,
    float* __restrict__ out,
    int n)
{
    const int row = blockIdx.x;
    const int tid = threadIdx.x;

    const float4* __restrict__ wrow =
        reinterpret_cast<const float4*>(w + (size_t)row * (size_t)n);
    const float4* __restrict__ g4 = reinterpret_cast<const float4*>(g);

    // --- issue the whole w-row slice first: NV outstanding dwordx4 per lane
    float4 wv[NV];
    #pragma unroll
    for (int i = 0; i < NV; ++i)
        wv[i] = wrow[tid + i * BLOCK];

    // --- g loads (L1-hit) + FMA chain consume the returning w data
    float acc0 = 0.0f, acc1 = 0.0f;
    #pragma unroll
    for (int i = 0; i < NV; ++i) {
        float4 gv = g4[tid + i * BLOCK];
        acc0 = fmaf(wv[i].x, gv.x, acc0);
        acc1 = fmaf(wv[i].y, gv.y, acc1);
        acc0 = fmaf(wv[i].z, gv.z, acc0);
        acc1 = fmaf(wv[i].w, gv.w, acc1);
    }
    float acc = acc0 + acc1;

    // --- wave (64-lane) butterfly reduce, then cross-wave via LDS ---------
    #pragma unroll
    for (int off = 32; off > 0; off >>= 1)
        acc += __shfl_down(acc, off, 64);

    __shared__ float partial[BLOCK / 64];
    const int wave = tid >> 6;
    const int lane = tid & 63;
    if (lane == 0) partial[wave] = acc;
    __syncthreads();

    // --- LIF elementwise update (lane 0 of block) -------------------------
    if (tid == 0) {
        float dot = 0.0f;
        #pragma unroll
        for (int i = 0; i < BLOCK / 64; ++i) dot += partial[i];

        const float I  = dot + x_in[row];
        const float vv = v[row];
        const float vr = v_rest[row];
        const float th = theta_s[row];

        // dv = v_rest - v + I/C_M ; v_next = v + dv
        const float v_next = vv + (vr - vv + I / 0.05f);

        // soft spike: sigmoid(v_next - theta_s)
        const float z = v_next - th;
        const float s_soft = 1.0f / (1.0f + expf(-z));

        // hard spike gating + reset
        const bool  spiked  = (v_next >= th);
        const float v_reset = vr + 0.15f * (vv - vr) - 12.0f;
        const float v_new   = spiked ? v_reset : v_next;

        out[row]     = v_new;
        out[n + row] = s_soft;
    }
}

// Generic fallback (runtime trip count) for n != 8192.
__global__ __launch_bounds__(BLOCK) void lif_r_fused_gen(
    const float* __restrict__ x_in,
    const float* __restrict__ v,
    const float* __restrict__ g,
    const float* __restrict__ theta_s,
    const float* __restrict__ w,
    const float* __restrict__ v_rest,
    float* __restrict__ out,
    int n)
{
    const int row = blockIdx.x;
    const int tid = threadIdx.x;

    const float4* __restrict__ wrow =
        reinterpret_cast<const float4*>(w + (size_t)row * (size_t)n);
    const float4* __restrict__ g4 = reinterpret_cast<const float4*>(g);

    const int nvec = n >> 2;
    float acc = 0.0f;
    for (int idx = tid; idx < nvec; idx += BLOCK) {
        float4 wv = wrow[idx];
        float4 gv = g4[idx];
        acc = fmaf(wv.x, gv.x, acc);
        acc = fmaf(wv.y, gv.y, acc);
        acc = fmaf(wv.z, gv.z, acc);
        acc = fmaf(wv.w, gv.w, acc);
    }

    #pragma unroll
    for (int off = 32; off > 0; off >>= 1)
        acc += __shfl_down(acc, off, 64);

    __shared__ float partial[BLOCK / 64];
    const int wave = tid >> 6;
    const int lane = tid & 63;
    if (lane == 0) partial[wave] = acc;
    __syncthreads();

    if (tid == 0) {
        float dot = 0.0f;
        #pragma unroll
        for (int i = 0; i < BLOCK / 64; ++i) dot += partial[i];

        const float I  = dot + x_in[row];
        const float vv = v[row];
        const float vr = v_rest[row];
        const float th = theta_s[row];

        const float v_next = vv + (vr - vv + I / 0.05f);
        const float z = v_next - th;
        const float s_soft = 1.0f / (1.0f + expf(-z));
        const bool  spiked  = (v_next >= th);
        const float v_reset = vr + 0.15f * (vv - vr) - 12.0f;
        const float v_new   = spiked ? v_reset : v_next;

        out[row]     = v_new;
        out[n + row] = s_soft;
    }
}

extern "C" void kernel_launch(void* const* d_in, const int* in_sizes, int n_in,
                              void* d_out, int out_size, void* d_ws, size_t ws_size,
                              hipStream_t stream) {
    // setup_inputs order: x_in, v, g, theta_s, w, v_rest, tau_g
    const float* x_in    = (const float*)d_in[0];
    const float* v       = (const float*)d_in[1];
    const float* g       = (const float*)d_in[2];
    const float* theta_s = (const float*)d_in[3];
    const float* w       = (const float*)d_in[4];
    const float* v_rest  = (const float*)d_in[5];
    // d_in[6] (tau_g) only affects hidden state g_new -> unused.

    const int n = in_sizes[0];            // 8192
    float* out = (float*)d_out;           // [v_new | spiked_soft]

    if (n == 8192) {
        // float4 elems per thread = 8192/4/256 = 8
        lif_r_fused<8><<<n, BLOCK, 0, stream>>>(x_in, v, g, theta_s, w, v_rest, out, n);
    } else {
        lif_r_fused_gen<<<n, BLOCK, 0, stream>>>(x_in, v, g, theta_s, w, v_rest, out, n);
    }
}

// Round 5
// 358.237 us; speedup vs baseline: 1.0070x; 1.0055x over previous
//
#include <hip/hip_runtime.h>
#include <math.h>

// LIF-R neuron step, N=8192.
// Dominant cost: w @ g matvec (256 MiB fp32, read once -> HBM-bound, ~43 us roofline).
// Outputs: d_out = [v_new (N), spiked_soft (N)] as float32.
// Hidden state (g_new, theta_new, tau_g) never observable -> not computed.
//
// R5 = R4 resubmit (infra timeout, never ran):
// 4 rows per block (grid 2048), g held in registers across rows
// (g L1 traffic /4), per-row 8-deep w-load issue, 4 interleaved butterfly
// reduces + single __syncthreads, LIF update parallel across 4 lanes.

#define BLOCK 256

template <int NV, int ROWS>  // NV = float4 elems of a row per thread
__global__ __launch_bounds__(BLOCK) void lif_r_fused(
    const float* __restrict__ x_in,
    const float* __restrict__ v,
    const float* __restrict__ g,
    const float* __restrict__ theta_s,
    const float* __restrict__ w,
    const float* __restrict__ v_rest,
    float* __restrict__ out,
    int n)
{
    const int row0 = blockIdx.x * ROWS;
    const int tid  = threadIdx.x;

    const float4* __restrict__ g4 = reinterpret_cast<const float4*>(g);

    // --- g slice into registers ONCE for all ROWS rows -------------------
    float4 gv[NV];
    #pragma unroll
    for (int i = 0; i < NV; ++i)
        gv[i] = g4[tid + i * BLOCK];

    float acc[ROWS];
    #pragma unroll
    for (int r = 0; r < ROWS; ++r) acc[r] = 0.0f;

    // --- per row: issue all NV w-loads, then FMA against resident g ------
    #pragma unroll
    for (int r = 0; r < ROWS; ++r) {
        const float4* __restrict__ wrow =
            reinterpret_cast<const float4*>(w + (size_t)(row0 + r) * (size_t)n);
        float4 wv[NV];
        #pragma unroll
        for (int i = 0; i < NV; ++i)
            wv[i] = wrow[tid + i * BLOCK];
        #pragma unroll
        for (int i = 0; i < NV; ++i) {
            acc[r] = fmaf(wv[i].x, gv[i].x, acc[r]);
            acc[r] = fmaf(wv[i].y, gv[i].y, acc[r]);
            acc[r] = fmaf(wv[i].z, gv[i].z, acc[r]);
            acc[r] = fmaf(wv[i].w, gv[i].w, acc[r]);
        }
    }

    // --- ROWS interleaved 64-lane butterfly reduces (ILP) ----------------
    #pragma unroll
    for (int off = 32; off > 0; off >>= 1) {
        #pragma unroll
        for (int r = 0; r < ROWS; ++r)
            acc[r] += __shfl_down(acc[r], off, 64);
    }

    __shared__ float partial[BLOCK / 64][ROWS];
    const int wave = tid >> 6;
    const int lane = tid & 63;
    if (lane == 0) {
        #pragma unroll
        for (int r = 0; r < ROWS; ++r) partial[wave][r] = acc[r];
    }
    __syncthreads();

    // --- LIF update: one lane per row -----------------------------------
    if (tid < ROWS) {
        const int row = row0 + tid;
        float dot = 0.0f;
        #pragma unroll
        for (int wv_ = 0; wv_ < BLOCK / 64; ++wv_) dot += partial[wv_][tid];

        const float I  = dot + x_in[row];
        const float vv = v[row];
        const float vr = v_rest[row];
        const float th = theta_s[row];

        // dv = v_rest - v + I/C_M ; v_next = v + dv
        const float v_next = vv + (vr - vv + I / 0.05f);

        // soft spike: sigmoid(v_next - theta_s)
        const float z = v_next - th;
        const float s_soft = 1.0f / (1.0f + expf(-z));

        // hard spike gating + reset
        const bool  spiked  = (v_next >= th);
        const float v_reset = vr + 0.15f * (vv - vr) - 12.0f;
        const float v_new   = spiked ? v_reset : v_next;

        out[row]     = v_new;
        out[n + row] = s_soft;
    }
}

// Generic fallback (runtime trip count) for n not divisible by configuration.
__global__ __launch_bounds__(BLOCK) void lif_r_fused_gen(
    const float* __restrict__ x_in,
    const float* __restrict__ v,
    const float* __restrict__ g,
    const float* __restrict__ theta_s,
    const float* __restrict__ w,
    const float* __restrict__ v_rest,
    float* __restrict__ out,
    int n)
{
    const int row = blockIdx.x;
    const int tid = threadIdx.x;

    const float4* __restrict__ wrow =
        reinterpret_cast<const float4*>(w + (size_t)row * (size_t)n);
    const float4* __restrict__ g4 = reinterpret_cast<const float4*>(g);

    const int nvec = n >> 2;
    float acc = 0.0f;
    for (int idx = tid; idx < nvec; idx += BLOCK) {
        float4 wv = wrow[idx];
        float4 gv = g4[idx];
        acc = fmaf(wv.x, gv.x, acc);
        acc = fmaf(wv.y, gv.y, acc);
        acc = fmaf(wv.z, gv.z, acc);
        acc = fmaf(wv.w, gv.w, acc);
    }

    #pragma unroll
    for (int off = 32; off > 0; off >>= 1)
        acc += __shfl_down(acc, off, 64);

    __shared__ float partial[BLOCK / 64];
    const int wave = tid >> 6;
    const int lane = tid & 63;
    if (lane == 0) partial[wave] = acc;
    __syncthreads();

    if (tid == 0) {
        float dot = 0.0f;
        #pragma unroll
        for (int i = 0; i < BLOCK / 64; ++i) dot += partial[i];

        const float I  = dot + x_in[row];
        const float vv = v[row];
        const float vr = v_rest[row];
        const float th = theta_s[row];

        const float v_next = vv + (vr - vv + I / 0.05f);
        const float z = v_next - th;
        const float s_soft = 1.0f / (1.0f + expf(-z));
        const bool  spiked  = (v_next >= th);
        const float v_reset = vr + 0.15f * (vv - vr) - 12.0f;
        const float v_new   = spiked ? v_reset : v_next;

        out[row]     = v_new;
        out[n + row] = s_soft;
    }
}

extern "C" void kernel_launch(void* const* d_in, const int* in_sizes, int n_in,
                              void* d_out, int out_size, void* d_ws, size_t ws_size,
                              hipStream_t stream) {
    // setup_inputs order: x_in, v, g, theta_s, w, v_rest, tau_g
    const float* x_in    = (const float*)d_in[0];
    const float* v       = (const float*)d_in[1];
    const float* g       = (const float*)d_in[2];
    const float* theta_s = (const float*)d_in[3];
    const float* w       = (const float*)d_in[4];
    const float* v_rest  = (const float*)d_in[5];
    // d_in[6] (tau_g) only affects hidden state g_new -> unused.

    const int n = in_sizes[0];            // 8192
    float* out = (float*)d_out;           // [v_new | spiked_soft]

    if (n == 8192) {
        // 8192/4/256 = 8 float4 per lane per row; 4 rows/block -> 2048 blocks
        lif_r_fused<8, 4><<<n / 4, BLOCK, 0, stream>>>(
            x_in, v, g, theta_s, w, v_rest, out, n);
    } else {
        lif_r_fused_gen<<<n, BLOCK, 0, stream>>>(x_in, v, g, theta_s, w, v_rest, out, n);
    }
}